// Round 16
// baseline (419.097 us; speedup 1.0000x reference)
//
#include <hip/hip_runtime.h>
#include <hip/hip_bf16.h>
#include <hip/hip_cooperative_groups.h>

namespace cg = cooperative_groups;

// GrantGCN: out = [h, A h] @ W2^T + b2, h = relu([x, A x] @ W1^T + b1)
// A built from edges with numpy semantics:
//   adj[src,dst] = w   (scatter-SET: last edge in order wins per (src,dst))
//   adj[dst,src] += w  (scatter-ADD: all edges accumulate)
// Round-16: single cooperative mega-kernel (1024 blocks x 256 = 262144 thr,
// 4 blocks/CU x 4 waves = 16 waves/CU; launch_bounds(256,4) caps VGPR at 128).
// Fixes round-5 (occupancy collapse: 8 waves/CU, 4 serial nodes) and round-6
// (2048-block coop launch failed silently) — return code checked, falls back
// to the proven 70.4us 4-dispatch pipeline.
// Phases (grid.sync between): P0 zero cnt + x->bf16 | P1 role-split build
// (tid<NE: add-entry, else set-entry) | P2 fusedA 2 nodes/wave | P3 fusedB.
// ELL rows segregated: add-entries up from 0 (cnt lo16), set-entries down
// from 95 (cnt hi16). Winner = max edge id per col, in-wave LDS scan.

#define NN    8192
#define NE    131072
#define XD    32
#define HID   64
#define NC    40
#define ESTR  96          // ELL row stride (entries)
#define CMASK 0x1FFFu     // col: bits 0..12; e+1 (18 bits) in bits 13..30

__device__ __forceinline__ unsigned f2b(float f) {   // f32 -> bf16 (RNE)
    const unsigned u = __float_as_uint(f);
    return (u + 0x7FFFu + ((u >> 16) & 1u)) >> 16;
}
__device__ __forceinline__ float blo(unsigned w) { return __uint_as_float(w << 16); }
__device__ __forceinline__ float bhi(unsigned w) { return __uint_as_float(w & 0xFFFF0000u); }

struct Params {
    const int*   src;
    const int*   dst;
    const float* w;
    const float* x;
    const float* W1;
    const float* b1;
    const float* W2;
    const float* b2;
    unsigned*    cnt;
    uint2*       ell;
    uint4*       xb;
    ushort*      hb;
    float*       out;
};

__global__ __launch_bounds__(256, 4) void mega(Params p) {
    cg::grid_group grid = cg::this_grid();
    const int t   = threadIdx.x;
    const int tid = blockIdx.x * 256 + t;     // 0..262143
    const int g   = t >> 6;                   // wave slot 0..3
    const int l   = t & 63;

    __shared__ float4   gc[4][32];            // wave-private staging
    __shared__ unsigned sx[4][64];            // wave-private set-region words

    // ---- P0: zero cnt (32 KiB) + convert x f32->bf16 ----
    if (tid < NN / 4) ((uint4*)p.cnt)[tid] = make_uint4(0u, 0u, 0u, 0u);
    if (tid < NN * XD / 8) {                  // 32768 threads
        const float4* x4 = (const float4*)p.x;
        const float4 a = x4[2 * tid], b = x4[2 * tid + 1];
        uint4 r;
        r.x = f2b(a.x) | (f2b(a.y) << 16);
        r.y = f2b(a.z) | (f2b(a.w) << 16);
        r.z = f2b(b.x) | (f2b(b.y) << 16);
        r.w = f2b(b.z) | (f2b(b.w) << 16);
        p.xb[tid] = r;
    }
    grid.sync();

    // ---- P1: build, role-split (262144 = 2*NE threads exactly) ----
    {
        const int e = tid & (NE - 1);
        const int s = p.src[e], d = p.dst[e];
        const unsigned wb = __float_as_uint(p.w[e]);
        if (tid < NE) {
            const unsigned q1 = atomicAdd(&p.cnt[d], 1u) & 0xFFFFu;
            if (q1 < ESTR) p.ell[d * ESTR + q1] = make_uint2((unsigned)s, wb);
        } else {
            const unsigned q2 = atomicAdd(&p.cnt[s], 0x10000u) >> 16;
            if (q2 < ESTR)
                p.ell[s * ESTR + (ESTR - 1u - q2)] =
                    make_uint2((unsigned)d | ((unsigned)(e + 1) << 13), wb);
        }
    }
    grid.sync();

    // ---- P2: fusedA — 2 nodes per wave ----
    const int wv = tid >> 6;                  // 0..4095
    {
        const int eq = l >> 2, fq = l & 3;    // 16 edge slots x 4 chunks
        const float4* x4 = (const float4*)p.x;
        for (int it = 0; it < 2; ++it) {
            const int n = wv * 2 + it;
            const unsigned c2 = p.cnt[n];
            const unsigned lo = min(c2 & 0xFFFFu, (unsigned)ESTR);
            const unsigned hi = min(c2 >> 16, 64u);
            uint2* row = &p.ell[n * ESTR];
            if (l < hi) sx[g][l] = row[ESTR - hi + l].x;
            __syncthreads();
            float a[8];
#pragma unroll
            for (int j = 0; j < 8; ++j) a[j] = 0.f;
            for (unsigned i = eq; i < lo; i += 16) {
                const uint2 ce = row[i];
                const float v = __uint_as_float(ce.y);
                const uint4 xv = p.xb[(ce.x & CMASK) * 4 + fq];
                a[0] += v * blo(xv.x); a[1] += v * bhi(xv.x);
                a[2] += v * blo(xv.y); a[3] += v * bhi(xv.y);
                a[4] += v * blo(xv.z); a[5] += v * bhi(xv.z);
                a[6] += v * blo(xv.w); a[7] += v * bhi(xv.w);
            }
            for (unsigned k = eq; k < hi; k += 16) {
                const uint2 ce = row[ESTR - hi + k];
                float v = __uint_as_float(ce.y);
                const uint4 xv = p.xb[(ce.x & CMASK) * 4 + fq];
                bool loser = false;
                for (unsigned j = 0; j < hi; ++j) {
                    const unsigned o = sx[g][j];
                    if (((o ^ ce.x) & CMASK) == 0u && (o >> 13) > (ce.x >> 13))
                        loser = true;
                }
                if (loser) {
                    v = 0.f;
                    if (fq == 0) ((unsigned*)&row[ESTR - hi + k])[1] = 0u;
                }
                a[0] += v * blo(xv.x); a[1] += v * bhi(xv.x);
                a[2] += v * blo(xv.y); a[3] += v * bhi(xv.y);
                a[4] += v * blo(xv.z); a[5] += v * bhi(xv.z);
                a[6] += v * blo(xv.w); a[7] += v * bhi(xv.w);
            }
#pragma unroll
            for (int mm = 4; mm < 64; mm <<= 1) {
#pragma unroll
                for (int j = 0; j < 8; ++j) a[j] += __shfl_xor(a[j], mm);
            }
            if (l < 4) {
                gc[g][8 + 2 * l] = make_float4(a[0], a[1], a[2], a[3]);
                gc[g][9 + 2 * l] = make_float4(a[4], a[5], a[6], a[7]);
            }
            if (l < 8) gc[g][l] = x4[n * 8 + l];
            __syncthreads();
            const float4* w4 = (const float4*)&p.W1[l * (2 * XD)];
            float acc = p.b1[l];
#pragma unroll
            for (int j = 0; j < 16; ++j) {
                const float4 gv = gc[g][j];
                const float4 wvv = w4[j];
                acc += gv.x * wvv.x + gv.y * wvv.y + gv.z * wvv.z + gv.w * wvv.w;
            }
            p.hb[n * HID + l] = (ushort)f2b(fmaxf(acc, 0.f));
        }
    }
    grid.sync();

    // ---- P3: fusedB — 2 nodes per wave ----
    {
        const int eq = l >> 2, fq = l & 3;    // 16 edge slots x chunk-pair
        const uint4* hb4 = (const uint4*)p.hb;
        for (int it = 0; it < 2; ++it) {
            const int n = wv * 2 + it;
            const unsigned c2 = p.cnt[n];
            const unsigned lo = min(c2 & 0xFFFFu, (unsigned)ESTR);
            const unsigned hi = min(c2 >> 16, 64u);
            const uint2* row = &p.ell[n * ESTR];
            float a[16];
#pragma unroll
            for (int j = 0; j < 16; ++j) a[j] = 0.f;
            for (unsigned i = eq; i < lo; i += 16) {
                const uint2 ce = row[i];
                const float v = __uint_as_float(ce.y);
                const unsigned c = ce.x & CMASK;
                const uint4 h0 = hb4[c * 8 + fq];
                const uint4 h1 = hb4[c * 8 + fq + 4];
                a[0] += v * blo(h0.x); a[1]  += v * bhi(h0.x);
                a[2] += v * blo(h0.y); a[3]  += v * bhi(h0.y);
                a[4] += v * blo(h0.z); a[5]  += v * bhi(h0.z);
                a[6] += v * blo(h0.w); a[7]  += v * bhi(h0.w);
                a[8] += v * blo(h1.x); a[9]  += v * bhi(h1.x);
                a[10]+= v * blo(h1.y); a[11] += v * bhi(h1.y);
                a[12]+= v * blo(h1.z); a[13] += v * bhi(h1.z);
                a[14]+= v * blo(h1.w); a[15] += v * bhi(h1.w);
            }
            for (unsigned k = eq; k < hi; k += 16) {
                const uint2 ce = row[ESTR - hi + k];
                const float v = __uint_as_float(ce.y);
                const unsigned c = ce.x & CMASK;
                const uint4 h0 = hb4[c * 8 + fq];
                const uint4 h1 = hb4[c * 8 + fq + 4];
                a[0] += v * blo(h0.x); a[1]  += v * bhi(h0.x);
                a[2] += v * blo(h0.y); a[3]  += v * bhi(h0.y);
                a[4] += v * blo(h0.z); a[5]  += v * bhi(h0.z);
                a[6] += v * blo(h0.w); a[7]  += v * bhi(h0.w);
                a[8] += v * blo(h1.x); a[9]  += v * bhi(h1.x);
                a[10]+= v * blo(h1.y); a[11] += v * bhi(h1.y);
                a[12]+= v * blo(h1.z); a[13] += v * bhi(h1.z);
                a[14]+= v * blo(h1.w); a[15] += v * bhi(h1.w);
            }
#pragma unroll
            for (int mm = 4; mm < 64; mm <<= 1) {
#pragma unroll
                for (int j = 0; j < 16; ++j) a[j] += __shfl_xor(a[j], mm);
            }
            if (l < 4) {
                gc[g][16 + 2 * l] = make_float4(a[0],  a[1],  a[2],  a[3]);
                gc[g][17 + 2 * l] = make_float4(a[4],  a[5],  a[6],  a[7]);
                gc[g][24 + 2 * l] = make_float4(a[8],  a[9],  a[10], a[11]);
                gc[g][25 + 2 * l] = make_float4(a[12], a[13], a[14], a[15]);
            }
            if (l < 8) {
                const uint4 hv = hb4[n * 8 + l];
                gc[g][2 * l]     = make_float4(blo(hv.x), bhi(hv.x), blo(hv.y), bhi(hv.y));
                gc[g][2 * l + 1] = make_float4(blo(hv.z), bhi(hv.z), blo(hv.w), bhi(hv.w));
            }
            __syncthreads();
            if (l < NC) {
                const float4* w4 = (const float4*)&p.W2[l * (2 * HID)];
                float acc = p.b2[l];
#pragma unroll
                for (int j = 0; j < 32; ++j) {
                    const float4 gv = gc[g][j];
                    const float4 wvv = w4[j];
                    acc += gv.x * wvv.x + gv.y * wvv.y + gv.z * wvv.z + gv.w * wvv.w;
                }
                p.out[n * NC + l] = acc;
            }
            __syncthreads();
        }
    }
}

// ------------------- fallback pipeline (round-15, proven 70.4us) -----------

__global__ __launch_bounds__(256) void init_conv(uint4* __restrict__ cnt4,
                                                 const float4* __restrict__ x4,
                                                 uint4* __restrict__ xb) {
    const int t = blockIdx.x * 256 + threadIdx.x;
    if (t < NN / 4) cnt4[t] = make_uint4(0u, 0u, 0u, 0u);
    const float4 a = x4[2 * t], b = x4[2 * t + 1];
    uint4 r;
    r.x = f2b(a.x) | (f2b(a.y) << 16);
    r.y = f2b(a.z) | (f2b(a.w) << 16);
    r.z = f2b(b.x) | (f2b(b.y) << 16);
    r.w = f2b(b.z) | (f2b(b.w) << 16);
    xb[t] = r;
}

__global__ __launch_bounds__(256) void build(const int* __restrict__ src,
                                             const int* __restrict__ dst,
                                             const float* __restrict__ w,
                                             unsigned* __restrict__ cnt,
                                             uint2* __restrict__ ell) {
    const int b = blockIdx.x;
    const int e = ((b & 511) << 8) | threadIdx.x;
    const int s = src[e], d = dst[e];
    const unsigned wb = __float_as_uint(w[e]);
    if (b < 512) {
        const unsigned q1 = atomicAdd(&cnt[d], 1u) & 0xFFFFu;
        if (q1 < ESTR) ell[d * ESTR + q1] = make_uint2((unsigned)s, wb);
    } else {
        const unsigned q2 = atomicAdd(&cnt[s], 0x10000u) >> 16;
        if (q2 < ESTR)
            ell[s * ESTR + (ESTR - 1u - q2)] =
                make_uint2((unsigned)d | ((unsigned)(e + 1) << 13), wb);
    }
}

__global__ __launch_bounds__(256) void fusedA(const unsigned* __restrict__ cnt,
                                              uint2* __restrict__ ell,
                                              const uint4* __restrict__ xb,
                                              const float4* __restrict__ x4,
                                              const float* __restrict__ W1,
                                              const float* __restrict__ b1,
                                              ushort* __restrict__ hb) {
    __shared__ float4 gc[4][16];
    __shared__ unsigned sx[4][64];
    const int t = threadIdx.x;
    const int g = t >> 6;
    const int l = t & 63;
    const int n = blockIdx.x * 4 + g;
    const int eq = l >> 2;
    const int fq = l & 3;
    const unsigned c2 = cnt[n];
    const unsigned lo = min(c2 & 0xFFFFu, (unsigned)ESTR);
    const unsigned hi = min(c2 >> 16, 64u);
    uint2* row = &ell[n * ESTR];
    if (l < hi) sx[g][l] = row[ESTR - hi + l].x;
    __syncthreads();
    float a[8];
#pragma unroll
    for (int j = 0; j < 8; ++j) a[j] = 0.f;
    for (unsigned i = eq; i < lo; i += 16) {
        const uint2 ce = row[i];
        const float v = __uint_as_float(ce.y);
        const uint4 xv = xb[(ce.x & CMASK) * 4 + fq];
        a[0] += v * blo(xv.x); a[1] += v * bhi(xv.x);
        a[2] += v * blo(xv.y); a[3] += v * bhi(xv.y);
        a[4] += v * blo(xv.z); a[5] += v * bhi(xv.z);
        a[6] += v * blo(xv.w); a[7] += v * bhi(xv.w);
    }
    for (unsigned k = eq; k < hi; k += 16) {
        const uint2 ce = row[ESTR - hi + k];
        float v = __uint_as_float(ce.y);
        const uint4 xv = xb[(ce.x & CMASK) * 4 + fq];
        bool loser = false;
        for (unsigned j = 0; j < hi; ++j) {
            const unsigned o = sx[g][j];
            if (((o ^ ce.x) & CMASK) == 0u && (o >> 13) > (ce.x >> 13)) loser = true;
        }
        if (loser) {
            v = 0.f;
            if (fq == 0) ((unsigned*)&row[ESTR - hi + k])[1] = 0u;
        }
        a[0] += v * blo(xv.x); a[1] += v * bhi(xv.x);
        a[2] += v * blo(xv.y); a[3] += v * bhi(xv.y);
        a[4] += v * blo(xv.z); a[5] += v * bhi(xv.z);
        a[6] += v * blo(xv.w); a[7] += v * bhi(xv.w);
    }
#pragma unroll
    for (int mm = 4; mm < 64; mm <<= 1) {
#pragma unroll
        for (int j = 0; j < 8; ++j) a[j] += __shfl_xor(a[j], mm);
    }
    if (l < 4) {
        gc[g][8 + 2 * l] = make_float4(a[0], a[1], a[2], a[3]);
        gc[g][9 + 2 * l] = make_float4(a[4], a[5], a[6], a[7]);
    }
    if (l < 8) gc[g][l] = x4[n * 8 + l];
    __syncthreads();
    const float4* w4 = (const float4*)&W1[l * (2 * XD)];
    float acc = b1[l];
#pragma unroll
    for (int j = 0; j < 16; ++j) {
        const float4 gv = gc[g][j];
        const float4 wv = w4[j];
        acc += gv.x * wv.x + gv.y * wv.y + gv.z * wv.z + gv.w * wv.w;
    }
    hb[n * HID + l] = (ushort)f2b(fmaxf(acc, 0.f));
}

__global__ __launch_bounds__(256) void fusedB(const unsigned* __restrict__ cnt,
                                              const uint2* __restrict__ ell,
                                              const uint4* __restrict__ hb4,
                                              const float* __restrict__ W2,
                                              const float* __restrict__ b2,
                                              float* __restrict__ out) {
    __shared__ float4 gc[4][32];
    const int t = threadIdx.x;
    const int g = t >> 6;
    const int l = t & 63;
    const int n = blockIdx.x * 4 + g;
    const int eq = l >> 2;
    const int fq = l & 3;
    const unsigned c2 = cnt[n];
    const unsigned lo = min(c2 & 0xFFFFu, (unsigned)ESTR);
    const unsigned hi = min(c2 >> 16, 64u);
    const uint2* row = &ell[n * ESTR];
    float a[16];
#pragma unroll
    for (int j = 0; j < 16; ++j) a[j] = 0.f;
    for (unsigned i = eq; i < lo; i += 16) {
        const uint2 ce = row[i];
        const float v = __uint_as_float(ce.y);
        const unsigned c = ce.x & CMASK;
        const uint4 h0 = hb4[c * 8 + fq];
        const uint4 h1 = hb4[c * 8 + fq + 4];
        a[0] += v * blo(h0.x); a[1]  += v * bhi(h0.x);
        a[2] += v * blo(h0.y); a[3]  += v * bhi(h0.y);
        a[4] += v * blo(h0.z); a[5]  += v * bhi(h0.z);
        a[6] += v * blo(h0.w); a[7]  += v * bhi(h0.w);
        a[8] += v * blo(h1.x); a[9]  += v * bhi(h1.x);
        a[10]+= v * blo(h1.y); a[11] += v * bhi(h1.y);
        a[12]+= v * blo(h1.z); a[13] += v * bhi(h1.z);
        a[14]+= v * blo(h1.w); a[15] += v * bhi(h1.w);
    }
    for (unsigned k = eq; k < hi; k += 16) {
        const uint2 ce = row[ESTR - hi + k];
        const float v = __uint_as_float(ce.y);
        const unsigned c = ce.x & CMASK;
        const uint4 h0 = hb4[c * 8 + fq];
        const uint4 h1 = hb4[c * 8 + fq + 4];
        a[0] += v * blo(h0.x); a[1]  += v * bhi(h0.x);
        a[2] += v * blo(h0.y); a[3]  += v * bhi(h0.y);
        a[4] += v * blo(h0.z); a[5]  += v * bhi(h0.z);
        a[6] += v * blo(h0.w); a[7]  += v * bhi(h0.w);
        a[8] += v * blo(h1.x); a[9]  += v * bhi(h1.x);
        a[10]+= v * blo(h1.y); a[11] += v * bhi(h1.y);
        a[12]+= v * blo(h1.z); a[13] += v * bhi(h1.z);
        a[14]+= v * blo(h1.w); a[15] += v * bhi(h1.w);
    }
#pragma unroll
    for (int mm = 4; mm < 64; mm <<= 1) {
#pragma unroll
        for (int j = 0; j < 16; ++j) a[j] += __shfl_xor(a[j], mm);
    }
    if (l < 4) {
        gc[g][16 + 2 * l] = make_float4(a[0],  a[1],  a[2],  a[3]);
        gc[g][17 + 2 * l] = make_float4(a[4],  a[5],  a[6],  a[7]);
        gc[g][24 + 2 * l] = make_float4(a[8],  a[9],  a[10], a[11]);
        gc[g][25 + 2 * l] = make_float4(a[12], a[13], a[14], a[15]);
    }
    if (l < 8) {
        const uint4 hv = hb4[n * 8 + l];
        gc[g][2 * l]     = make_float4(blo(hv.x), bhi(hv.x), blo(hv.y), bhi(hv.y));
        gc[g][2 * l + 1] = make_float4(blo(hv.z), bhi(hv.z), blo(hv.w), bhi(hv.w));
    }
    __syncthreads();
    if (l < NC) {
        const float4* w4 = (const float4*)&W2[l * (2 * HID)];
        float acc = b2[l];
#pragma unroll
        for (int j = 0; j < 32; ++j) {
            const float4 gv = gc[g][j];
            const float4 wv = w4[j];
            acc += gv.x * wv.x + gv.y * wv.y + gv.z * wv.z + gv.w * wv.w;
        }
        out[n * NC + l] = acc;
    }
}

extern "C" void kernel_launch(void* const* d_in, const int* in_sizes, int n_in,
                              void* d_out, int out_size, void* d_ws, size_t ws_size,
                              hipStream_t stream) {
    char* ws = (char*)d_ws;
    Params p;
    p.src = (const int*)d_in[1];
    p.dst = (const int*)d_in[1] + NE;
    p.w   = (const float*)d_in[2];
    p.x   = (const float*)d_in[0];
    // d_in[3] is k (always 2)
    p.W1  = (const float*)d_in[4];
    p.b1  = (const float*)d_in[5];
    p.W2  = (const float*)d_in[6];
    p.b2  = (const float*)d_in[7];
    p.cnt = (unsigned*)(ws + 0);                                      // 32 KiB
    p.ell = (uint2*)   (ws + (64 << 10));                             // 6 MiB
    p.xb  = (uint4*)   (ws + (64 << 10) + (6 << 20));                 // 512 KiB
    p.hb  = (ushort*)  (ws + (64 << 10) + (6 << 20) + (512 << 10));   // 1 MiB
    p.out = (float*)d_out;

    void* args[] = {&p};
    hipError_t err = hipLaunchCooperativeKernel((const void*)mega, dim3(1024),
                                                dim3(256), args, 0, stream);
    if (err != hipSuccess) {
        (void)hipGetLastError();   // clear sticky error; use proven pipeline
        init_conv<<<128, 256, 0, stream>>>((uint4*)p.cnt, (const float4*)p.x, p.xb);
        build<<<1024, 256, 0, stream>>>(p.src, p.dst, p.w, p.cnt, p.ell);
        fusedA<<<NN / 4, 256, 0, stream>>>(p.cnt, p.ell, p.xb, (const float4*)p.x,
                                           p.W1, p.b1, p.hb);
        fusedB<<<NN / 4, 256, 0, stream>>>(p.cnt, p.ell, (const uint4*)p.hb,
                                           p.W2, p.b2, p.out);
    }
}

// Round 17
// 70.350 us; speedup vs baseline: 5.9573x; 5.9573x over previous
//
#include <hip/hip_runtime.h>
#include <hip/hip_bf16.h>

// GrantGCN: out = [h, A h] @ W2^T + b2, h = relu([x, A x] @ W1^T + b1)
// A built from edges with numpy semantics:
//   adj[src,dst] = w   (scatter-SET: last edge in order wins per (src,dst))
//   adj[dst,src] += w  (scatter-ADD: all edges accumulate)
// Round-17: final structure. Cost model (fits rounds 4-16): ~10-12us fixed
// per graph dispatch + ~25us kernel work; coop grid.sync measured ~130us per
// barrier (R5/R16) so 4 dispatches is optimal. This round: dispatch 1 shrunk
// to a pure 32KiB zero (8 blocks); x->bf16 conversion folded into build.
//   1 zero_cnt : cnt <- 0 (8 blocks)
//   2 build    : role-split (blocks 0..511 add-entries, 512..1023 set-entries);
//                blocks 0..127 also convert x f32->bf16
//   3 fusedA   : wave/node gather y1=(A x)[n] (bf16) + dense1 + relu -> h (bf16)
//   4 fusedB   : wave/node gather y2=(A h)[n] (bf16) + dense2 -> out (f32)
// ELL rows segregated: add-entries up from 0 (cnt lo16), set-entries down from
// 95 (cnt hi16). Winner = max edge id per col, resolved in-wave via LDS scan
// of the set-region (losers' w zero-written by fusedA for fusedB).

#define NN    8192
#define NE    131072
#define XD    32
#define HID   64
#define NC    40
#define ESTR  96          // ELL row stride (entries)
#define CMASK 0x1FFFu     // col: bits 0..12; e+1 (18 bits) in bits 13..30

__device__ __forceinline__ unsigned f2b(float f) {   // f32 -> bf16 (RNE)
    const unsigned u = __float_as_uint(f);
    return (u + 0x7FFFu + ((u >> 16) & 1u)) >> 16;
}
__device__ __forceinline__ float blo(unsigned w) { return __uint_as_float(w << 16); }
__device__ __forceinline__ float bhi(unsigned w) { return __uint_as_float(w & 0xFFFF0000u); }

// zero cnt: 8192 dwords = 2048 uint4; 8 blocks x 256 threads.
__global__ __launch_bounds__(256) void zero_cnt(uint4* __restrict__ cnt4) {
    cnt4[blockIdx.x * 256 + threadIdx.x] = make_uint4(0u, 0u, 0u, 0u);
}

// build, role-split: blocks 0..511 write add-entries (row dst, slots up from
// 0, cnt lo16); blocks 512..1023 write set-entries (row src, slots down from
// 95, cnt hi16, edge id packed). Blocks 0..127 also convert x f32->bf16.
__global__ __launch_bounds__(256) void build(const int* __restrict__ src,
                                             const int* __restrict__ dst,
                                             const float* __restrict__ w,
                                             const float4* __restrict__ x4,
                                             unsigned* __restrict__ cnt,
                                             uint2* __restrict__ ell,
                                             uint4* __restrict__ xb) {
    const int b = blockIdx.x;
    const int t = threadIdx.x;
    const int e = ((b & 511) << 8) | t;   // 0..NE-1
    if (b < 128) {                         // fold x -> bf16 (32768 threads)
        const int c = b * 256 + t;
        const float4 a0 = x4[2 * c], a1 = x4[2 * c + 1];
        uint4 r;
        r.x = f2b(a0.x) | (f2b(a0.y) << 16);
        r.y = f2b(a0.z) | (f2b(a0.w) << 16);
        r.z = f2b(a1.x) | (f2b(a1.y) << 16);
        r.w = f2b(a1.z) | (f2b(a1.w) << 16);
        xb[c] = r;
    }
    const int s = src[e], d = dst[e];
    const unsigned wb = __float_as_uint(w[e]);
    if (b < 512) {
        const unsigned q1 = atomicAdd(&cnt[d], 1u) & 0xFFFFu;
        if (q1 < ESTR) ell[d * ESTR + q1] = make_uint2((unsigned)s, wb);
    } else {
        const unsigned q2 = atomicAdd(&cnt[s], 0x10000u) >> 16;
        if (q2 < ESTR)
            ell[s * ESTR + (ESTR - 1u - q2)] =
                make_uint2((unsigned)d | ((unsigned)(e + 1) << 13), wb);
    }
}

// fusedA: one 64-lane wave per node. Lane = (edge-slot eq 0..15, chunk fq 0..3).
// Gathers bf16 x rows (4 x uint4 per row); set-region winners resolved via
// LDS-staged in-wave scan (losers' w zero-written for fusedB). Then xor-reduce
// over 16 slots, stage concat(x_n, y1_n) in LDS (f32), dense1+relu -> h (bf16).
__global__ __launch_bounds__(256) void fusedA(const unsigned* __restrict__ cnt,
                                              uint2* __restrict__ ell,
                                              const uint4* __restrict__ xb,
                                              const float4* __restrict__ x4,
                                              const float* __restrict__ W1,
                                              const float* __restrict__ b1,
                                              ushort* __restrict__ hb) {
    __shared__ float4 gc[4][16];    // per wave: quads 0..7 = x row, 8..15 = y1
    __shared__ unsigned sx[4][64];  // per wave: staged set-region .x words
    const int t = threadIdx.x;
    const int g = t >> 6;           // wave slot 0..3
    const int l = t & 63;
    const int n = blockIdx.x * 4 + g;
    const int eq = l >> 2;          // edge slot 0..15
    const int fq = l & 3;           // 16B chunk 0..3 (8 bf16 features each)
    const unsigned c2 = cnt[n];
    const unsigned lo = min(c2 & 0xFFFFu, (unsigned)ESTR);
    const unsigned hi = min(c2 >> 16, 64u);
    uint2* row = &ell[n * ESTR];

    if (l < hi) sx[g][l] = row[ESTR - hi + l].x;
    __syncthreads();

    float a[8];
#pragma unroll
    for (int j = 0; j < 8; ++j) a[j] = 0.f;

    // add-region: always contributes
    for (unsigned i = eq; i < lo; i += 16) {
        const uint2 ce = row[i];
        const float v = __uint_as_float(ce.y);
        const uint4 xv = xb[(ce.x & CMASK) * 4 + fq];
        a[0] += v * blo(xv.x); a[1] += v * bhi(xv.x);
        a[2] += v * blo(xv.y); a[3] += v * bhi(xv.y);
        a[4] += v * blo(xv.z); a[5] += v * bhi(xv.z);
        a[6] += v * blo(xv.w); a[7] += v * bhi(xv.w);
    }
    // set-region: winner = max edge id per col (in-wave scan of staged words)
    for (unsigned k = eq; k < hi; k += 16) {
        const uint2 ce = row[ESTR - hi + k];
        float v = __uint_as_float(ce.y);
        const uint4 xv = xb[(ce.x & CMASK) * 4 + fq];
        bool loser = false;
        for (unsigned j = 0; j < hi; ++j) {
            const unsigned o = sx[g][j];
            if (((o ^ ce.x) & CMASK) == 0u && (o >> 13) > (ce.x >> 13)) loser = true;
        }
        if (loser) {
            v = 0.f;
            if (fq == 0) ((unsigned*)&row[ESTR - hi + k])[1] = 0u;  // persist
        }
        a[0] += v * blo(xv.x); a[1] += v * bhi(xv.x);
        a[2] += v * blo(xv.y); a[3] += v * bhi(xv.y);
        a[4] += v * blo(xv.z); a[5] += v * bhi(xv.z);
        a[6] += v * blo(xv.w); a[7] += v * bhi(xv.w);
    }
#pragma unroll
    for (int mm = 4; mm < 64; mm <<= 1) {
#pragma unroll
        for (int j = 0; j < 8; ++j) a[j] += __shfl_xor(a[j], mm);
    }
    if (l < 4) {                   // lane fq holds features [fq*8, fq*8+8)
        gc[g][8 + 2 * l] = make_float4(a[0], a[1], a[2], a[3]);
        gc[g][9 + 2 * l] = make_float4(a[4], a[5], a[6], a[7]);
    }
    if (l < 8) gc[g][l] = x4[n * 8 + l];   // self x row (f32)
    __syncthreads();
    // dense1: lane l = hidden unit l of node n; h out in bf16
    const float4* w4 = (const float4*)&W1[l * (2 * XD)];
    float acc = b1[l];
#pragma unroll
    for (int j = 0; j < 16; ++j) {
        const float4 gv = gc[g][j];
        const float4 wv = w4[j];
        acc += gv.x * wv.x + gv.y * wv.y + gv.z * wv.z + gv.w * wv.w;
    }
    hb[n * HID + l] = (ushort)f2b(fmaxf(acc, 0.f));
}

// fusedB: one 64-lane wave per node. Lane = (edge-slot eq 0..15, chunk-pair
// fq 0..3: chunks fq and fq+4). 2 independent uint4 loads per entry.
// Set-entries already resolved (.y is w or 0). Then dense2 -> out (f32).
__global__ __launch_bounds__(256) void fusedB(const unsigned* __restrict__ cnt,
                                              const uint2* __restrict__ ell,
                                              const uint4* __restrict__ hb4,
                                              const float* __restrict__ W2,
                                              const float* __restrict__ b2,
                                              float* __restrict__ out) {
    __shared__ float4 gc[4][32];   // per wave: quads 0..15 = h row, 16..31 = y2
    const int t = threadIdx.x;
    const int g = t >> 6;
    const int l = t & 63;
    const int n = blockIdx.x * 4 + g;
    const int eq = l >> 2;         // edge slot 0..15
    const int fq = l & 3;          // chunk pair: chunks fq and fq+4
    const unsigned c2 = cnt[n];
    const unsigned lo = min(c2 & 0xFFFFu, (unsigned)ESTR);
    const unsigned hi = min(c2 >> 16, 64u);
    const uint2* row = &ell[n * ESTR];
    float a[16];
#pragma unroll
    for (int j = 0; j < 16; ++j) a[j] = 0.f;

    for (unsigned i = eq; i < lo; i += 16) {
        const uint2 ce = row[i];
        const float v = __uint_as_float(ce.y);
        const unsigned c = ce.x & CMASK;
        const uint4 h0 = hb4[c * 8 + fq];
        const uint4 h1 = hb4[c * 8 + fq + 4];
        a[0] += v * blo(h0.x); a[1]  += v * bhi(h0.x);
        a[2] += v * blo(h0.y); a[3]  += v * bhi(h0.y);
        a[4] += v * blo(h0.z); a[5]  += v * bhi(h0.z);
        a[6] += v * blo(h0.w); a[7]  += v * bhi(h0.w);
        a[8] += v * blo(h1.x); a[9]  += v * bhi(h1.x);
        a[10]+= v * blo(h1.y); a[11] += v * bhi(h1.y);
        a[12]+= v * blo(h1.z); a[13] += v * bhi(h1.z);
        a[14]+= v * blo(h1.w); a[15] += v * bhi(h1.w);
    }
    for (unsigned k = eq; k < hi; k += 16) {
        const uint2 ce = row[ESTR - hi + k];
        const float v = __uint_as_float(ce.y);
        const unsigned c = ce.x & CMASK;
        const uint4 h0 = hb4[c * 8 + fq];
        const uint4 h1 = hb4[c * 8 + fq + 4];
        a[0] += v * blo(h0.x); a[1]  += v * bhi(h0.x);
        a[2] += v * blo(h0.y); a[3]  += v * bhi(h0.y);
        a[4] += v * blo(h0.z); a[5]  += v * bhi(h0.z);
        a[6] += v * blo(h0.w); a[7]  += v * bhi(h0.w);
        a[8] += v * blo(h1.x); a[9]  += v * bhi(h1.x);
        a[10]+= v * blo(h1.y); a[11] += v * bhi(h1.y);
        a[12]+= v * blo(h1.z); a[13] += v * bhi(h1.z);
        a[14]+= v * blo(h1.w); a[15] += v * bhi(h1.w);
    }
#pragma unroll
    for (int mm = 4; mm < 64; mm <<= 1) {
#pragma unroll
        for (int j = 0; j < 16; ++j) a[j] += __shfl_xor(a[j], mm);
    }
    if (l < 4) {
        gc[g][16 + 2 * l] = make_float4(a[0],  a[1],  a[2],  a[3]);
        gc[g][17 + 2 * l] = make_float4(a[4],  a[5],  a[6],  a[7]);
        gc[g][24 + 2 * l] = make_float4(a[8],  a[9],  a[10], a[11]);   // chunk fq+4
        gc[g][25 + 2 * l] = make_float4(a[12], a[13], a[14], a[15]);
    }
    if (l < 8) {                   // self h row (bf16 -> f32), chunk l
        const uint4 hv = hb4[n * 8 + l];
        gc[g][2 * l]     = make_float4(blo(hv.x), bhi(hv.x), blo(hv.y), bhi(hv.y));
        gc[g][2 * l + 1] = make_float4(blo(hv.z), bhi(hv.z), blo(hv.w), bhi(hv.w));
    }
    __syncthreads();
    if (l < NC) {
        const float4* w4 = (const float4*)&W2[l * (2 * HID)];
        float acc = b2[l];
#pragma unroll
        for (int j = 0; j < 32; ++j) {
            const float4 gv = gc[g][j];
            const float4 wv = w4[j];
            acc += gv.x * wv.x + gv.y * wv.y + gv.z * wv.z + gv.w * wv.w;
        }
        out[n * NC + l] = acc;
    }
}

extern "C" void kernel_launch(void* const* d_in, const int* in_sizes, int n_in,
                              void* d_out, int out_size, void* d_ws, size_t ws_size,
                              hipStream_t stream) {
    const float* x  = (const float*)d_in[0];
    const int*   ei = (const int*)d_in[1];
    const float* w  = (const float*)d_in[2];
    // d_in[3] is k (always 2)
    const float* W1 = (const float*)d_in[4];
    const float* b1 = (const float*)d_in[5];
    const float* W2 = (const float*)d_in[6];
    const float* b2 = (const float*)d_in[7];
    float* out = (float*)d_out;

    char* ws = (char*)d_ws;
    unsigned* cnt = (unsigned*)(ws + 0);                        // 32 KiB
    uint2*    ell = (uint2*)   (ws + (64 << 10));               // 6 MiB
    uint4*    xb  = (uint4*)   (ws + (64 << 10) + (6 << 20));   // 512 KiB (bf16 x)
    ushort*   hb  = (ushort*)  (ws + (64 << 10) + (6 << 20) + (512 << 10)); // 1 MiB (bf16 h)

    const int* src = ei;        // edge_index[0, :]
    const int* dst = ei + NE;   // edge_index[1, :]

    zero_cnt<<<8, 256, 0, stream>>>((uint4*)cnt);
    build<<<1024, 256, 0, stream>>>(src, dst, w, (const float4*)x, cnt, ell, xb);
    fusedA<<<NN / 4, 256, 0, stream>>>(cnt, ell, xb, (const float4*)x, W1, b1, hb);
    fusedB<<<NN / 4, 256, 0, stream>>>(cnt, ell, (const uint4*)hb, W2, b2, out);
}